// Round 8
// baseline (118.989 us; speedup 1.0000x reference)
//
#include <hip/hip_runtime.h>

#define HWC 4096
#define WC 64
#define HC 64
#define DC 256
#define BC 2
#define KKC 81
#define NBIN 128      // 16 y-cells (4 rows) x 8 x-cells (8 cols) per batch
#define SLOTS 221     // region: 13 rows x 17 cols of pixel-columns
#define SLOT_H 264    // _Float16 per slot: 256 data + 8 pad (528 B stride)

typedef _Float16 h2 __attribute__((ext_vector_type(2)));
typedef _Float16 h8 __attribute__((ext_vector_type(8)));

static __device__ inline float dot8(h8 v, h8 a, float s) {
#if __has_builtin(__builtin_amdgcn_fdot2)
    s = __builtin_amdgcn_fdot2((h2){v[0], v[1]}, (h2){a[0], a[1]}, s, false);
    s = __builtin_amdgcn_fdot2((h2){v[2], v[3]}, (h2){a[2], a[3]}, s, false);
    s = __builtin_amdgcn_fdot2((h2){v[4], v[5]}, (h2){a[4], a[5]}, s, false);
    s = __builtin_amdgcn_fdot2((h2){v[6], v[7]}, (h2){a[6], a[7]}, s, false);
#else
#pragma unroll
    for (int k = 0; k < 8; ++k) s += (float)v[k] * (float)a[k];
#endif
    return s;
}

// x += x[other lane in 16-lane row], VALU-pipe DPP; ctrl must be a literal.
#define DPP_ADD(x, ctrl) \
    ((x) + __int_as_float(__builtin_amdgcn_update_dpp(0, __float_as_int(x), (ctrl), 0xF, 0xF, true)))

// ------- transpose+cast BOTH maps: [B, D, HW] f32 -> [B, HW, D] f16 -------
__global__ __launch_bounds__(256) void transpose_h_k(const float* __restrict__ f1,
                                                     const float* __restrict__ f2,
                                                     _Float16* __restrict__ o1,
                                                     _Float16* __restrict__ o2) {
    __shared__ float tile[64][33];
    const int z = blockIdx.z;               // z = map*2 + b
    const int b = z & 1;
    const float* in = (z >> 1) ? f2 : f1;
    _Float16* out = (z >> 1) ? o2 : o1;
    in += (size_t)b * DC * HWC;
    out += (size_t)b * HWC * DC;

    const int m0 = blockIdx.x * 32, d0 = blockIdx.y * 64;
    const int tid = threadIdx.x;
    const int tx = tid & 31, ty = tid >> 5;
#pragma unroll
    for (int k = 0; k < 8; ++k)
        tile[ty + k * 8][tx] = in[(size_t)(d0 + ty + k * 8) * HWC + m0 + tx];
    __syncthreads();

    const int dx = tid & 7, my = tid >> 3;
    h8 v;
#pragma unroll
    for (int e = 0; e < 8; ++e) v[e] = (_Float16)tile[dx * 8 + e][my];
    *(h8*)(out + (size_t)(m0 + my) * DC + d0 + dx * 8) = v;
}

// ------- counting sort of pixels into 128 centroid cells (4y x 8x pixels) -------
__global__ __launch_bounds__(1024) void sort_k(const float* __restrict__ coords,
                                               int* __restrict__ sorted,
                                               int* __restrict__ off) {
    __shared__ int hist[NBIN];
    __shared__ int base[NBIN];
    const int b = blockIdx.x;
    const int tid = threadIdx.x;
    if (tid < NBIN) hist[tid] = 0;
    __syncthreads();
    int key[4];
#pragma unroll
    for (int k = 0; k < 4; ++k) {
        const int hw = tid * 4 + k;
        const float x = coords[((size_t)b * 2 + 0) * HWC + hw];
        const float y = coords[((size_t)b * 2 + 1) * HWC + hw];
        const int cx = min(max((int)floorf(x), 0), 63) >> 3;
        const int cy = min(max((int)floorf(y), 0), 63) >> 2;
        key[k] = cy * 8 + cx;
        atomicAdd(&hist[key[k]], 1);
    }
    __syncthreads();
    if (tid == 0) {
        int acc = 0;
        for (int i = 0; i < NBIN; ++i) { base[i] = acc; acc += hist[i]; }
    }
    __syncthreads();
    if (tid < NBIN) off[b * (NBIN + 1) + tid] = base[tid];
    if (tid == 0) off[b * (NBIN + 1) + NBIN] = HWC;
    __syncthreads();   // off written before base is mutated below
#pragma unroll
    for (int k = 0; k < 4; ++k) {
        const int pos = atomicAdd(&base[key[k]], 1);
        sorted[b * HWC + pos] = tid * 4 + k;
    }
}

// ---------------- binned neighborhood-corr + bilinear ----------------
// One block per (batch, cell); stages the cell's 13x17 sample region into LDS
// once, then each wave processes pixels of the bin independently (no block
// barriers in the pixel loop). 4 groups x 16 lanes per wave; group g computes
// cells [g*25, g*25+25) of the 10x10 patch from LDS; DPP reduce; per-wave Cs.
// RAFT quirk: out[n, i, j] samples at x = x_c + (i-4), y = y_c + (j-4).
__global__ __launch_bounds__(256, 1) void corr_k(const _Float16* __restrict__ f1t,
                                                 const _Float16* __restrict__ f2t,
                                                 const float* __restrict__ coords,
                                                 const int* __restrict__ sorted,
                                                 const int* __restrict__ off,
                                                 float* __restrict__ out) {
    __shared__ _Float16 patch[SLOTS * SLOT_H];  // 116,688 B
    __shared__ float Cs[4][112];

    const int bid = blockIdx.x;
    const int b = bid >> 7, cell = bid & 127;
    const int cy = cell >> 3, cx = cell & 7;
    const int oy = cy * 4 - 4, ox = cx * 8 - 4;  // region origin (logical)
    const int tid = threadIdx.x;

    // ---- stage region: slot s holds f2t column of clamped (oy+ly, ox+lx) ----
    const h8* f2b = (const h8*)f2t + (size_t)b * HWC * 32;
    {
        const int sl = tid >> 4, l16 = tid & 15;
        for (int s = sl; s < SLOTS; s += 16) {
            const int ly = s / 17, lx = s - ly * 17;
            const int gy = min(max(oy + ly, 0), HC - 1);
            const int gx = min(max(ox + lx, 0), WC - 1);
            const h8* src = f2b + (size_t)(gy * WC + gx) * 32 + l16 * 2;
            const h8 u0 = src[0], u1 = src[1];
            h8* dst = (h8*)(patch + s * SLOT_H) + l16 * 2;
            dst[0] = u0; dst[1] = u1;
        }
    }
    const int start = off[b * (NBIN + 1) + cell];
    const int end   = off[b * (NBIN + 1) + cell + 1];
    __syncthreads();

    const int wv = tid >> 6, l = tid & 63;
    const int g = (tid >> 4) & 3, il = tid & 15;

    for (int p = start + wv; p < end; p += 4) {
        const int hw = sorted[b * HWC + p];
        const float x = coords[((size_t)b * 2 + 0) * HWC + hw];
        const float y = coords[((size_t)b * 2 + 1) * HWC + hw];
        const float x0f = floorf(x), y0f = floorf(y);
        const float wx = x - x0f, wy = y - y0f;
        const int ix0 = (int)x0f, iy0 = (int)y0f;
        const int dy = iy0 - 4 - oy;   // base local row for yi=0, in [0,3]
        const int dx = ix0 - 4 - ox;   // base local col for xi=0, in [0,7]

        // f1 fragment: d = il*8..+8 and 128+il*8..+8 (order-agnostic dot)
        const _Float16* f1c = f1t + ((size_t)(b * HWC) + hw) * DC;
        const h8 a0 = *(const h8*)(f1c + il * 8);
        const h8 a1 = *(const h8*)(f1c + 128 + il * 8);

#pragma unroll
        for (int i = 0; i < 25; ++i) {
            const int t = g * 25 + i;
            const int yi = t / 10, xi = t - yi * 10;
            const int slot = (dy + yi) * 17 + (dx + xi);
            const _Float16* pp = patch + slot * SLOT_H + il * 8;
            const h8 v0 = *(const h8*)pp;
            const h8 v1 = *(const h8*)(pp + 128);
            const int gy = iy0 - 4 + yi, gx = ix0 - 4 + xi;
            const float vm = (((unsigned)gy < (unsigned)HC) &
                              ((unsigned)gx < (unsigned)WC)) ? 0.0625f : 0.f;
            float s = dot8(v0, a0, 0.f);
            s = dot8(v1, a1, s);
            s *= vm;
            s = DPP_ADD(s, 0xB1);    // quad_perm xor1
            s = DPP_ADD(s, 0x4E);    // quad_perm xor2
            s = DPP_ADD(s, 0x124);   // row_ror:4
            s = DPP_ADD(s, 0x128);   // row_ror:8
            if (il == 0) Cs[wv][t] = s;
        }
#if __has_builtin(__builtin_amdgcn_wave_barrier)
        __builtin_amdgcn_wave_barrier();   // keep LDS write->read order (same wave)
#else
        __builtin_amdgcn_sched_barrier(0);
#endif
        // ---- bilinear combine (i walks x, j walks y — RAFT quirk) ----
        const float w00 = (1.f - wx) * (1.f - wy);
        const float w01 = wx * (1.f - wy);
        const float w10 = (1.f - wx) * wy;
        const float w11 = wx * wy;
        {
            const int k = l, i = k / 9, j = k - (k / 9) * 9;
            const float r = w00 * Cs[wv][j * 10 + i]       + w01 * Cs[wv][j * 10 + i + 1] +
                            w10 * Cs[wv][(j + 1) * 10 + i] + w11 * Cs[wv][(j + 1) * 10 + i + 1];
            out[((size_t)(b * KKC + k)) * HWC + hw] = r;
        }
        if (l < KKC - 64) {
            const int k = 64 + l, i = k / 9, j = k - (k / 9) * 9;
            const float r = w00 * Cs[wv][j * 10 + i]       + w01 * Cs[wv][j * 10 + i + 1] +
                            w10 * Cs[wv][(j + 1) * 10 + i] + w11 * Cs[wv][(j + 1) * 10 + i + 1];
            out[((size_t)(b * KKC + k)) * HWC + hw] = r;
        }
    }
}

extern "C" void kernel_launch(void* const* d_in, const int* in_sizes, int n_in,
                              void* d_out, int out_size, void* d_ws, size_t ws_size,
                              hipStream_t stream) {
    const float* fmap1 = (const float*)d_in[0];
    const float* fmap2 = (const float*)d_in[1];
    const float* coords = (const float*)d_in[2];
    float* out = (float*)d_out;

    const size_t perH = (size_t)BC * HWC * DC;  // f16 elements per transposed map
    _Float16* f1t = (_Float16*)d_ws;
    _Float16* f2t = f1t + perH;
    int* sorted = (int*)(f2t + perH);           // [B][HW]
    int* off = sorted + BC * HWC;               // [B][NBIN+1]

    transpose_h_k<<<dim3(HWC / 32, DC / 64, 4), dim3(256), 0, stream>>>(fmap1, fmap2, f1t, f2t);
    sort_k<<<dim3(BC), dim3(1024), 0, stream>>>(coords, sorted, off);
    corr_k<<<dim3(BC * NBIN), dim3(256), 0, stream>>>(f1t, f2t, coords, sorted, off, out);
}

// Round 9
// 101.066 us; speedup vs baseline: 1.1773x; 1.1773x over previous
//
#include <hip/hip_runtime.h>

#define HWC 4096
#define WC 64
#define HC 64
#define DC 256
#define BC 2
#define KKC 81
#define NBIN 128      // 16 y-cells (4 rows) x 8 x-cells (8 cols) per batch
#define NSLOT 221     // region: 13 rows x 17 cols of f2 columns
#define NPCH 32       // pixels per MFMA chunk (2 M-tiles)
#define CSTR 228      // Cs row stride (floats)

typedef _Float16 h8 __attribute__((ext_vector_type(8)));
typedef float f4 __attribute__((ext_vector_type(4)));

// ------- transpose+cast BOTH maps: [B, D, HW] f32 -> [B, HW, D] f16 -------
__global__ __launch_bounds__(256) void transpose_h_k(const float* __restrict__ f1,
                                                     const float* __restrict__ f2,
                                                     _Float16* __restrict__ o1,
                                                     _Float16* __restrict__ o2) {
    __shared__ float tile[64][33];
    const int z = blockIdx.z;               // z = map*2 + b
    const int b = z & 1;
    const float* in = (z >> 1) ? f2 : f1;
    _Float16* out = (z >> 1) ? o2 : o1;
    in += (size_t)b * DC * HWC;
    out += (size_t)b * HWC * DC;

    const int m0 = blockIdx.x * 32, d0 = blockIdx.y * 64;
    const int tid = threadIdx.x;
    const int tx = tid & 31, ty = tid >> 5;
#pragma unroll
    for (int k = 0; k < 8; ++k)
        tile[ty + k * 8][tx] = in[(size_t)(d0 + ty + k * 8) * HWC + m0 + tx];
    __syncthreads();

    const int dx = tid & 7, my = tid >> 3;
    h8 v;
#pragma unroll
    for (int e = 0; e < 8; ++e) v[e] = (_Float16)tile[dx * 8 + e][my];
    *(h8*)(out + (size_t)(m0 + my) * DC + d0 + dx * 8) = v;
}

// ------- counting sort of pixels into 128 centroid cells (4y x 8x pixels) -------
__global__ __launch_bounds__(1024) void sort_k(const float* __restrict__ coords,
                                               int* __restrict__ sorted,
                                               int* __restrict__ off) {
    __shared__ int hist[NBIN];
    __shared__ int base[NBIN];
    const int b = blockIdx.x;
    const int tid = threadIdx.x;
    if (tid < NBIN) hist[tid] = 0;
    __syncthreads();
    int key[4];
#pragma unroll
    for (int k = 0; k < 4; ++k) {
        const int hw = tid * 4 + k;
        const float x = coords[((size_t)b * 2 + 0) * HWC + hw];
        const float y = coords[((size_t)b * 2 + 1) * HWC + hw];
        const int cx = min(max((int)floorf(x), 0), 63) >> 3;
        const int cy = min(max((int)floorf(y), 0), 63) >> 2;
        key[k] = cy * 8 + cx;
        atomicAdd(&hist[key[k]], 1);
    }
    __syncthreads();
    if (tid == 0) {
        int acc = 0;
        for (int i = 0; i < NBIN; ++i) { base[i] = acc; acc += hist[i]; }
    }
    __syncthreads();
    if (tid < NBIN) off[b * (NBIN + 1) + tid] = base[tid];
    if (tid == 0) off[b * (NBIN + 1) + NBIN] = HWC;
    __syncthreads();   // off written before base is mutated below
#pragma unroll
    for (int k = 0; k < 4; ++k) {
        const int pos = atomicAdd(&base[key[k]], 1);
        sorted[b * HWC + pos] = tid * 4 + k;
    }
}

// ---------------- binned MFMA corr + bilinear ----------------
// One 1024-thread block per (batch, cell). Per 32-pixel chunk:
//   C[pixel][slot] = f1[pixel] . f2[slot]  for all 221 region slots, computed
//   as an MFMA GEMM (M=32 pixels, N=224 slots, K=256), fragments straight from
//   L2, accumulators written to LDS Cs; then per-pixel bilinear combine with
//   per-corner validity * 1/sqrt(D) scale.
// MFMA 16x16x32_f16 lane layout: A: lane l -> A[l&15][(l>>4)*8+e];
// B: lane l -> B[(l>>4)*8+e][l&15]; D: lane l -> D[(l>>4)*4+r][l&15] (m89).
// RAFT quirk: out[n, i, j] samples at x = x_c + (i-4), y = y_c + (j-4).
__global__ __launch_bounds__(1024, 4) void corr_k(const _Float16* __restrict__ f1t,
                                                  const _Float16* __restrict__ f2t,
                                                  const float* __restrict__ coords,
                                                  const int* __restrict__ sorted,
                                                  const int* __restrict__ off,
                                                  float* __restrict__ out) {
    __shared__ float Cs[NPCH][CSTR];     // 29.2 KB
    __shared__ int pid[NPCH];
    __shared__ float pxs[NPCH], pys[NPCH];

    const int bid = blockIdx.x;
    const int b = bid >> 7, cell = bid & 127;
    const int cy = cell >> 3, cx = cell & 7;
    const int oy = cy * 4 - 4, ox = cx * 8 - 4;   // region origin (logical)

    const int tid = threadIdx.x;
    const int wv = tid >> 6, l = tid & 63;
    const int il = l & 15, kh = l >> 4;           // fragment lane decomposition

    const int start = off[b * (NBIN + 1) + cell];
    const int end   = off[b * (NBIN + 1) + cell + 1];

    const _Float16* f1b = f1t + (size_t)b * HWC * DC;
    const _Float16* f2b = f2t + (size_t)b * HWC * DC;

    // wave roles: mt = M-tile (pixel half), nt0..nt0+1 = this wave's N-tiles
    const int mt = wv & 1;
    const int nt0 = (wv >> 1) * 2;

    // B-fragment column pointers (chunk-independent): slot -> clamped (gy,gx)
    const _Float16* bcol0;
    const _Float16* bcol1;
    {
#pragma unroll
        for (int q = 0; q < 2; ++q) {
            int slot = (nt0 + q) * 16 + il;
            slot = slot > NSLOT - 1 ? NSLOT - 1 : slot;
            const int ly = slot / 17, lx = slot - ly * 17;
            const int gy = min(max(oy + ly, 0), HC - 1);
            const int gx = min(max(ox + lx, 0), WC - 1);
            const _Float16* p = f2b + (size_t)(gy * WC + gx) * DC + kh * 8;
            if (q == 0) bcol0 = p; else bcol1 = p;
        }
    }

    for (int chunk = start; chunk < end; chunk += NPCH) {
        const int npix = min(end - chunk, NPCH);
        if (tid < NPCH) {
            const int p = min(chunk + tid, end - 1);
            const int h = sorted[b * HWC + p];
            pid[tid] = h;
            pxs[tid] = coords[((size_t)b * 2 + 0) * HWC + h];
            pys[tid] = coords[((size_t)b * 2 + 1) * HWC + h];
        }
        __syncthreads();

        // ---- A fragments for this wave's M-tile (pixel rows) ----
        const _Float16* arow = f1b + (size_t)pid[mt * 16 + il] * DC + kh * 8;
        h8 af[8];
#pragma unroll
        for (int k = 0; k < 8; ++k) af[k] = *(const h8*)(arow + k * 32);

        // ---- MFMA: 2 N-tiles for this wave (skip padded nt >= 14) ----
#pragma unroll
        for (int q = 0; q < 2; ++q) {
            const int nt = nt0 + q;
            if (nt >= 14) break;
            const _Float16* bc = q == 0 ? bcol0 : bcol1;
            h8 bf[8];
#pragma unroll
            for (int k = 0; k < 8; ++k) bf[k] = *(const h8*)(bc + k * 32);
            f4 acc = {0.f, 0.f, 0.f, 0.f};
#pragma unroll
            for (int k = 0; k < 8; ++k)
                acc = __builtin_amdgcn_mfma_f32_16x16x32_f16(af[k], bf[k], acc, 0, 0, 0);
            const int row = mt * 16 + kh * 4;
            const int col = nt * 16 + il;
#pragma unroll
            for (int r = 0; r < 4; ++r) Cs[row + r][col] = acc[r];
        }
        __syncthreads();

        // ---- per-pixel bilinear combine (i walks x, j walks y — RAFT quirk) ----
        for (int pp = wv; pp < npix; pp += 16) {
            const int h = pid[pp];
            const float x = pxs[pp], y = pys[pp];
            const float x0f = floorf(x), y0f = floorf(y);
            const float wx = x - x0f, wy = y - y0f;
            const int ix0 = (int)x0f, iy0 = (int)y0f;
            const int dy = iy0 - 4 - oy, dx = ix0 - 4 - ox;   // dy in [0,3], dx in [0,7]
            const float w00 = (1.f - wx) * (1.f - wy);
            const float w01 = wx * (1.f - wy);
            const float w10 = (1.f - wx) * wy;
            const float w11 = wx * wy;
#pragma unroll
            for (int half = 0; half < 2; ++half) {
                if (half == 1 && l >= KKC - 64) break;
                const int k = half * 64 + l;
                const int i = k / 9, j = k - (k / 9) * 9;
                const int s00 = (dy + j) * 17 + (dx + i);
                const int gyj = iy0 - 4 + j, gxi = ix0 - 4 + i;
                const float vm00 = (((unsigned)gyj < (unsigned)HC) & ((unsigned)gxi < (unsigned)WC)) ? 0.0625f : 0.f;
                const float vm01 = (((unsigned)gyj < (unsigned)HC) & ((unsigned)(gxi + 1) < (unsigned)WC)) ? 0.0625f : 0.f;
                const float vm10 = (((unsigned)(gyj + 1) < (unsigned)HC) & ((unsigned)gxi < (unsigned)WC)) ? 0.0625f : 0.f;
                const float vm11 = (((unsigned)(gyj + 1) < (unsigned)HC) & ((unsigned)(gxi + 1) < (unsigned)WC)) ? 0.0625f : 0.f;
                const float r = w00 * vm00 * Cs[pp][s00]      + w01 * vm01 * Cs[pp][s00 + 1] +
                                w10 * vm10 * Cs[pp][s00 + 17] + w11 * vm11 * Cs[pp][s00 + 18];
                out[((size_t)(b * KKC + k)) * HWC + h] = r;
            }
        }
        __syncthreads();   // Cs/pid reused next chunk
    }
}

extern "C" void kernel_launch(void* const* d_in, const int* in_sizes, int n_in,
                              void* d_out, int out_size, void* d_ws, size_t ws_size,
                              hipStream_t stream) {
    const float* fmap1 = (const float*)d_in[0];
    const float* fmap2 = (const float*)d_in[1];
    const float* coords = (const float*)d_in[2];
    float* out = (float*)d_out;

    const size_t perH = (size_t)BC * HWC * DC;  // f16 elements per transposed map
    _Float16* f1t = (_Float16*)d_ws;
    _Float16* f2t = f1t + perH;
    int* sorted = (int*)(f2t + perH);           // [B][HW]
    int* off = sorted + BC * HWC;               // [B][NBIN+1]

    transpose_h_k<<<dim3(HWC / 32, DC / 64, 4), dim3(256), 0, stream>>>(fmap1, fmap2, f1t, f2t);
    sort_k<<<dim3(BC), dim3(1024), 0, stream>>>(coords, sorted, off);
    corr_k<<<dim3(BC * NBIN), dim3(1024), 0, stream>>>(f1t, f2t, coords, sorted, off, out);
}